// Round 4
// baseline (400.055 us; speedup 1.0000x reference)
//
#include <hip/hip_runtime.h>
#include <hip/hip_bf16.h>

typedef __attribute__((ext_vector_type(8))) __bf16 bf16x8;
typedef __attribute__((ext_vector_type(4))) float floatx4;
typedef __attribute__((ext_vector_type(8))) unsigned short ushort8;

namespace {
constexpr int kC  = 256;
constexpr int kNV = 1024 * 12;        // 12288
constexpr int kP  = 8 * kNV;          // 98304 positions
constexpr float kEps = 1e-5f;

// ws layout in float units
constexpr size_t OFF_PART   = 2048;                      // 4 stages x 8 buckets x 512
constexpr size_t OFF_WB     = 2048 + 16384;              // packed bf16 weights
constexpr size_t OFF_XT     = OFF_WB + 81920;            // x transposed [P][256] bf16 (pristine)
constexpr size_t OFF_Y1     = OFF_XT + (size_t)kP * 256 / 2;
constexpr size_t OFF_Y2     = OFF_Y1 + (size_t)kP * 64 / 2;   // [P][256] bf16 (also y4)
constexpr size_t OFF_Y3     = OFF_Y2 + (size_t)kP * 256 / 2;
} // namespace

__device__ __forceinline__ unsigned short f2bf(float f) {
    unsigned int u = __builtin_bit_cast(unsigned int, f);
    u += 0x7FFFu + ((u >> 16) & 1u);
    return (unsigned short)(u >> 16);
}
__device__ __forceinline__ float bf2f(unsigned short h) {
    unsigned int u = ((unsigned int)h) << 16;
    return __builtin_bit_cast(float, u);
}

// Pack the 4 weight matrices to bf16 in MFMA-fragment order:
// dst[base + (k/32)*(M*32) + m*32 + (k%32)]
__global__ void convw_kernel(const float* __restrict__ We, const float* __restrict__ Wa,
                             const float* __restrict__ Wo, const float* __restrict__ Wf,
                             unsigned short* __restrict__ dst)
{
    const int f = (blockIdx.x * 256 + threadIdx.x) * 4;
    const float* src; int off, M, K, base;
    if (f < 16384)      { src = We;            off = f;         M = 64;  K = 256; base = 0; }
    else if (f < 32768) { src = Wa + 512 * 64; off = f - 16384; M = 256; K = 64;  base = 16384; }
    else if (f < 98304) { src = Wo;            off = f - 32768; M = 256; K = 256; base = 32768; }
    else                { src = Wf;            off = f - 98304; M = 256; K = 256; base = 98304; }
    const int m = off / K, k = off - m * K;
    const float4 v = *(const float4*)&src[off];
    ushort4 o; o.x = f2bf(v.x); o.y = f2bf(v.y); o.z = f2bf(v.z); o.w = f2bf(v.w);
    *(ushort4*)&dst[base + (k >> 5) * (M * 32) + m * 32 + (k & 31)] = o;
}

// x [B,256,NV] fp32 channel-major -> xT [P][256] bf16 position-major
__global__ __launch_bounds__(256) void transpose_kernel(
    const float* __restrict__ x, unsigned short* __restrict__ xT)
{
    __shared__ float T[64][65];
    const int p0 = blockIdx.x * 64;
    const int c0 = blockIdx.y * 64;
    const int b  = p0 / kNV;
    const int q0 = p0 - b * kNV;
    const int t  = threadIdx.x;

    const int cl = t >> 2;
    const int pq = (t & 3) * 16;
    const float* src = &x[(size_t)(b * kC + c0 + cl) * kNV + q0 + pq];
    #pragma unroll
    for (int i = 0; i < 4; ++i) {
        const float4 v = *(const float4*)&src[i * 4];
        T[cl][pq + i * 4 + 0] = v.x;
        T[cl][pq + i * 4 + 1] = v.y;
        T[cl][pq + i * 4 + 2] = v.z;
        T[cl][pq + i * 4 + 3] = v.w;
    }
    __syncthreads();
    const int pr = t >> 2;
    const int cb = (t & 3) * 16;
    #pragma unroll
    for (int i = 0; i < 2; ++i) {
        ushort8 o;
        #pragma unroll
        for (int j = 0; j < 8; ++j) o[j] = f2bf(T[cb + i * 8 + j][pr]);
        *(ushort8*)&xT[(size_t)(p0 + pr) * 256 + c0 + cb + i * 8] = o;
    }
}

template<int MODE>
__device__ __forceinline__ ushort8 xform(ushort8 y8, ushort8 x8, float mp,
                                         const float* __restrict__ actA,
                                         const float* __restrict__ actB, int kk)
{
    if constexpr (MODE == 0) {
        return y8;
    } else {
        const float4 a0 = *(const float4*)&actA[kk];
        const float4 a1 = *(const float4*)&actA[kk + 4];
        const float4 b0 = *(const float4*)&actB[kk];
        const float4 b1 = *(const float4*)&actB[kk + 4];
        const float aa[8] = {a0.x, a0.y, a0.z, a0.w, a1.x, a1.y, a1.z, a1.w};
        const float bb[8] = {b0.x, b0.y, b0.z, b0.w, b1.x, b1.y, b1.z, b1.w};
        ushort8 o;
        #pragma unroll
        for (int j = 0; j < 8; ++j) {
            float v = bf2f(y8[j]);
            v = mp * fmaxf(fmaf(aa[j], v, bb[j]), 0.f);
            if constexpr (MODE == 2) v += bf2f(x8[j]);
            o[j] = f2bf(v);
        }
        return o;
    }
}

// A-stationary GEMM (round-2 structure). Block = 4 waves; wave owns BM/4 output
// channels with full-K A fragments in REGISTERS. B streams as 32-position slabs
// through a double-buffered LDS tile; one barrier per slab.
// SIBS sibling blocks split the MTOT output channels (BM=MTOT/SIBS each) for the
// same slab range; XCD-grouping swizzle (round-robin: bid%8 -> XCD) co-locates all
// siblings of a group on one XCD so the shared B-stream is HBM-read once and the
// other reads hit that XCD's L2. BM=64 -> Areg=32 VGPR -> 4 blocks/CU.
// BN affine of the PREVIOUS stage is computed per block in the prologue from the
// `part` buckets (finalize folded in).
// MODE 0: B = raw bf16. MODE 1: B = mask*relu(a*y+b). MODE 2: MODE1 + XT residual
// (XT read-only; x1 is NOT materialized).
template<int BM, int MTOT, int K, int MODE, int SIBS, int MINW>
__global__ __launch_bounds__(256, MINW) void gemm_kernel(
    const unsigned short* __restrict__ Apk, const float* __restrict__ bias,
    const unsigned short* __restrict__ Yprev, const unsigned short* __restrict__ XT,
    const float* __restrict__ mask,
    const float* __restrict__ pPrev, const float* __restrict__ gPrev,
    const float* __restrict__ btPrev,
    unsigned short* __restrict__ Yout, float* __restrict__ partial, int slabsPerBlock)
{
    constexpr int LD = 264;              // padded row stride (shorts): 2-way banks max
    constexpr int NT = K / 32;
    constexpr int FM = BM / 64;          // channels-per-wave / 16
    constexpr int FP = 2;                // 32 positions per slab
    constexpr int CH = K / 64;           // ushort8 chunks per thread per stream
    __shared__ unsigned short Bs[2][32 * LD];
    __shared__ float Sst[2][256];
    __shared__ float ActA[256];
    __shared__ float ActB[256];

    const int tid  = threadIdx.x;
    const int w    = tid >> 6, lane = tid & 63, quad = lane >> 4, lt = lane & 15;
    const int mBase = w * 16 * FM;

    Sst[0][tid] = 0.f; Sst[1][tid] = 0.f;

    // ---- block -> (group, sibling). Round-robin dispatch: bid%8 -> XCD bid%8;
    // siblings are 8 apart in bid -> same XCD, adjacent in dispatch order.
    int groupId, sib;
    if constexpr (SIBS > 1) {
        const int x = blockIdx.x & 7;
        const int s = blockIdx.x >> 3;
        const int perX = (int)(gridDim.x >> 3) / SIBS;
        sib = s % SIBS;
        groupId = x * perX + s / SIBS;
    } else {
        groupId = blockIdx.x; sib = 0;
    }
    const int chOff = sib * BM;
    const int slab0 = groupId * slabsPerBlock;

    // ---- fold previous stage's BN into per-channel affine (replaces finalize_kernel) ----
    if constexpr (MODE != 0) {
        if (tid < K) {
            float s = 0.f, s2 = 0.f;
            #pragma unroll
            for (int k = 0; k < 8; ++k) {
                s  += pPrev[k * 512 + tid];
                s2 += pPrev[k * 512 + 256 + tid];
            }
            const float mu  = s * (1.f / kP);
            const float var = s2 * (1.f / kP) - mu * mu;
            const float A   = rsqrtf(var + kEps) * gPrev[tid];
            ActA[tid] = A;
            ActB[tid] = fmaf(-mu, A, btPrev[tid]);
        }
        __syncthreads();
    }

    // ---- A fragments: full K for this block's channel slice, in registers ----
    ushort8 Areg[NT][FM];
    #pragma unroll
    for (int t = 0; t < NT; ++t)
        #pragma unroll
        for (int fm = 0; fm < FM; ++fm)
            Areg[t][fm] = *(const ushort8*)&Apk[(size_t)(t * MTOT + chOff + mBase + fm * 16 + lt) * 32 + quad * 8];

    const int spb = slabsPerBlock;

    // ---- prologue: stage slab 0 into Bs[0] ----
    {
        const int pBase = slab0 * 32;
        #pragma unroll
        for (int i = 0; i < CH; ++i) {
            const int c = tid + i * 256;
            const int p = c / (K / 8);
            const int kq = (c % (K / 8)) * 8;
            const ushort8 y8 = *(const ushort8*)&Yprev[(size_t)(pBase + p) * K + kq];
            ushort8 o;
            if constexpr (MODE == 0) o = y8;
            else {
                ushort8 x8{};
                if constexpr (MODE == 2) x8 = *(const ushort8*)&XT[(size_t)(pBase + p) * K + kq];
                o = xform<MODE>(y8, x8, mask[pBase + p], ActA, ActB, kq);
            }
            *(ushort8*)&Bs[0][p * LD + kq] = o;
        }
    }
    __syncthreads();

    for (int s = 0; s < spb; ++s) {
        const int pBase = (slab0 + s) * 32;
        const bool hasNext = (s + 1 < spb);

        // ---- prefetch next slab's streams into registers (latency covered by MFMAs) ----
        ushort8 py[CH];
        ushort8 px[(MODE == 2) ? CH : 1];
        if (hasNext) {
            const int pN = (slab0 + s + 1) * 32;
            #pragma unroll
            for (int i = 0; i < CH; ++i) {
                const int c = tid + i * 256;
                const int p = c / (K / 8);
                const int kq = (c % (K / 8)) * 8;
                py[i] = *(const ushort8*)&Yprev[(size_t)(pN + p) * K + kq];
                if constexpr (MODE == 2)
                    px[i] = *(const ushort8*)&XT[(size_t)(pN + p) * K + kq];
            }
        }

        // ---- MFMA over current slab: LDS-only inner loop ----
        floatx4 acc[FM][FP];
        #pragma unroll
        for (int fm = 0; fm < FM; ++fm)
            #pragma unroll
            for (int fp = 0; fp < FP; ++fp) acc[fm][fp] = (floatx4)0.f;

        const unsigned short* bs = &Bs[s & 1][0];
        #pragma unroll
        for (int t = 0; t < NT; ++t) {
            bf16x8 bF[FP];
            #pragma unroll
            for (int fp = 0; fp < FP; ++fp)
                bF[fp] = *(const bf16x8*)&bs[(fp * 16 + lt) * LD + t * 32 + quad * 8];
            #pragma unroll
            for (int fm = 0; fm < FM; ++fm) {
                const bf16x8 aF = __builtin_bit_cast(bf16x8, Areg[t][fm]);
                #pragma unroll
                for (int fp = 0; fp < FP; ++fp)
                    acc[fm][fp] = __builtin_amdgcn_mfma_f32_16x16x32_bf16(aF, bF[fp], acc[fm][fp], 0, 0, 0);
            }
        }

        // ---- epilogue: bias + mask, bf16 store, stats into LDS (owner lanes) ----
        float mpv[FP];
        #pragma unroll
        for (int fp = 0; fp < FP; ++fp) mpv[fp] = mask[pBase + fp * 16 + lt];

        float sS[FM][4], sQ[FM][4];
        #pragma unroll
        for (int fm = 0; fm < FM; ++fm)
            #pragma unroll
            for (int i = 0; i < 4; ++i) { sS[fm][i] = 0.f; sQ[fm][i] = 0.f; }

        #pragma unroll
        for (int fm = 0; fm < FM; ++fm) {
            const float4 bia = *(const float4*)&bias[chOff + mBase + fm * 16 + quad * 4];
            const float bi[4] = {bia.x, bia.y, bia.z, bia.w};
            #pragma unroll
            for (int fp = 0; fp < FP; ++fp) {
                const int pG = pBase + fp * 16 + lt;
                float vv[4];
                #pragma unroll
                for (int i = 0; i < 4; ++i) {
                    const float v = (acc[fm][fp][i] + bi[i]) * mpv[fp];
                    vv[i] = v; sS[fm][i] += v; sQ[fm][i] += v * v;
                }
                ushort4 o; o.x = f2bf(vv[0]); o.y = f2bf(vv[1]); o.z = f2bf(vv[2]); o.w = f2bf(vv[3]);
                *(ushort4*)&Yout[(size_t)pG * MTOT + chOff + mBase + fm * 16 + quad * 4] = o;
            }
        }
        #pragma unroll
        for (int fm = 0; fm < FM; ++fm)
            #pragma unroll
            for (int i = 0; i < 4; ++i) {
                #pragma unroll
                for (int off = 1; off < 16; off <<= 1) {
                    sS[fm][i] += __shfl_xor(sS[fm][i], off);
                    sQ[fm][i] += __shfl_xor(sQ[fm][i], off);
                }
            }
        if (lt == 0) {
            #pragma unroll
            for (int fm = 0; fm < FM; ++fm)
                #pragma unroll
                for (int i = 0; i < 4; ++i) {
                    const int ch = mBase + fm * 16 + quad * 4 + i;   // unique owner per local ch
                    Sst[0][ch] += sS[fm][i];
                    Sst[1][ch] += sQ[fm][i];
                }
        }

        // ---- xform prefetched data, write other LDS buffer ----
        if (hasNext) {
            const int pN = (slab0 + s + 1) * 32;
            unsigned short* bn = &Bs[(s + 1) & 1][0];
            #pragma unroll
            for (int i = 0; i < CH; ++i) {
                const int c = tid + i * 256;
                const int p = c / (K / 8);
                const int kq = (c % (K / 8)) * 8;
                ushort8 o;
                if constexpr (MODE == 0) o = py[i];
                else {
                    ushort8 x8{};
                    if constexpr (MODE == 2) x8 = px[i];
                    o = xform<MODE>(py[i], x8, mask[pN + p], ActA, ActB, kq);
                }
                *(ushort8*)&bn[p * LD + kq] = o;
            }
        }
        __syncthreads();
    }

    // ---- flush block stats (one bucketed atomic pass) ----
    if (tid < BM) {
        float* pb = partial + (size_t)(blockIdx.x & 7) * 512;
        atomicAdd(&pb[chOff + tid], Sst[0][tid]);
        atomicAdd(&pb[256 + chOff + tid], Sst[1][tid]);
    }
}

// out[c][q] = x1 + act4(y4), with x1 = x + act3(y3) recomputed on the fly.
// Both act3 and act4 affines computed in-prologue from the part buckets.
__global__ __launch_bounds__(256) void final_kernel(
    const unsigned short* __restrict__ xT, const unsigned short* __restrict__ y3,
    const unsigned short* __restrict__ y4,
    const float* __restrict__ p3, const float* __restrict__ g3, const float* __restrict__ bt3,
    const float* __restrict__ p4, const float* __restrict__ g4, const float* __restrict__ bt4,
    const float* __restrict__ mask, float* __restrict__ out)
{
    constexpr int TL = 264;
    __shared__ unsigned short TX[32 * TL];   // x1 (bf16)
    __shared__ unsigned short T4[32 * TL];   // y4 raw
    __shared__ float PA3[256], PB3[256], PA4[256], PB4[256];
    const int p0 = blockIdx.x * 32;
    const int b  = p0 / kNV;
    const int q0 = p0 - b * kNV;

    {
        const int m = threadIdx.x;
        float s3 = 0.f, q3 = 0.f, s4 = 0.f, q4 = 0.f;
        #pragma unroll
        for (int k = 0; k < 8; ++k) {
            s3 += p3[k * 512 + m]; q3 += p3[k * 512 + 256 + m];
            s4 += p4[k * 512 + m]; q4 += p4[k * 512 + 256 + m];
        }
        const float mu3 = s3 * (1.f / kP);
        const float A3  = rsqrtf(q3 * (1.f / kP) - mu3 * mu3 + kEps) * g3[m];
        PA3[m] = A3; PB3[m] = fmaf(-mu3, A3, bt3[m]);
        const float mu4 = s4 * (1.f / kP);
        const float A4  = rsqrtf(q4 * (1.f / kP) - mu4 * mu4 + kEps) * g4[m];
        PA4[m] = A4; PB4[m] = fmaf(-mu4, A4, bt4[m]);
    }
    __syncthreads();

    #pragma unroll
    for (int i = 0; i < 4; ++i) {
        const int idx = threadIdx.x + i * 256;
        const int p = idx >> 5, c0 = (idx & 31) * 8;
        const ushort8 x8  = *(const ushort8*)&xT[(size_t)(p0 + p) * 256 + c0];
        const ushort8 y38 = *(const ushort8*)&y3[(size_t)(p0 + p) * 256 + c0];
        const ushort8 y48 = *(const ushort8*)&y4[(size_t)(p0 + p) * 256 + c0];
        const float mp = mask[p0 + p];
        ushort8 o;
        #pragma unroll
        for (int j = 0; j < 8; ++j) {
            const int c = c0 + j;
            const float x1 = bf2f(x8[j]) + mp * fmaxf(fmaf(PA3[c], bf2f(y38[j]), PB3[c]), 0.f);
            o[j] = f2bf(x1);
        }
        *(ushort8*)&TX[p * TL + c0] = o;
        *(ushort8*)&T4[p * TL + c0] = y48;
    }
    __syncthreads();

    const int qv = (threadIdx.x & 15) * 2;
    const int cb = threadIdx.x >> 4;
    const float m0v = mask[p0 + qv], m1v = mask[p0 + qv + 1];
    #pragma unroll
    for (int j = 0; j < 16; ++j) {
        const int c = cb + j * 16;
        const float a4 = PA4[c], b4 = PB4[c];
        const size_t ro = (size_t)(b * kC + c) * kNV + q0 + qv;
        float2 o;
        o.x = bf2f(TX[qv * TL + c])       + m0v * fmaxf(fmaf(a4, bf2f(T4[qv * TL + c]), b4), 0.f);
        o.y = bf2f(TX[(qv + 1) * TL + c]) + m1v * fmaxf(fmaf(a4, bf2f(T4[(qv + 1) * TL + c]), b4), 0.f);
        *(float2*)&out[ro] = o;
    }
}

extern "C" void kernel_launch(void* const* d_in, const int* in_sizes, int n_in,
                              void* d_out, int out_size, void* d_ws, size_t ws_size,
                              hipStream_t stream)
{
    const float* x    = (const float*)d_in[0];
    const float* mask = (const float*)d_in[1];
    const float* We   = (const float*)d_in[2];
    const float* be   = (const float*)d_in[3];
    const float* ge   = (const float*)d_in[4];
    const float* bne  = (const float*)d_in[5];
    const float* Wa   = (const float*)d_in[6];
    const float* ba   = (const float*)d_in[7];
    const float* ga   = (const float*)d_in[8];
    const float* bna  = (const float*)d_in[9];
    const float* Wo   = (const float*)d_in[10];
    const float* bo   = (const float*)d_in[11];
    const float* go   = (const float*)d_in[12];
    const float* bno  = (const float*)d_in[13];
    const float* Wf   = (const float*)d_in[14];
    const float* bf   = (const float*)d_in[15];
    const float* gf   = (const float*)d_in[16];
    const float* bnf  = (const float*)d_in[17];
    float* out = (float*)d_out;
    float* ws  = (float*)d_ws;

    float* part = ws + OFF_PART;
    unsigned short* Wb = (unsigned short*)(ws + OFF_WB);
    unsigned short* xT = (unsigned short*)(ws + OFF_XT);
    unsigned short* y1 = (unsigned short*)(ws + OFF_Y1);
    unsigned short* y2 = (unsigned short*)(ws + OFF_Y2);   // later reused as y4
    unsigned short* y3 = (unsigned short*)(ws + OFF_Y3);

    hipMemsetAsync(part, 0, 16384 * sizeof(float), stream);
    convw_kernel<<<160, 256, 0, stream>>>(We, Wa, Wo, Wf, Wb);
    transpose_kernel<<<dim3(kP / 64, 4), 256, 0, stream>>>(x, xT);

    const dim3 blk(256);

    // stage 1: y1 = mask*(We @ x + be)  [P][64]
    gemm_kernel<64, 64, 256, 0, 1, 4><<<1024, blk, 0, stream>>>(
        Wb, be, xT, nullptr, mask, nullptr, nullptr, nullptr, y1, part, 3);

    // stage 2: y2 = mask*(Wa_v @ act1(y1) + ba_v)  [P][256]
    gemm_kernel<256, 256, 64, 1, 1, 4><<<1024, blk, 0, stream>>>(
        Wb + 16384, ba + 512, y1, nullptr, mask, part, ge, bne, y2, part + 4096, 3);

    // stage 3: y3 = mask*(Wo @ act2(y2) + bo)   4 sibling blocks/group, 4 blocks/CU
    gemm_kernel<64, 256, 256, 1, 4, 4><<<1024, blk, 0, stream>>>(
        Wb + 32768, bo, y2, nullptr, mask, part + 4096, ga + 512, bna + 512, y3, part + 8192, 12);

    // stage 4: y4 = mask*(Wf @ (x + act3(y3)) + bf)   XT read-only
    gemm_kernel<64, 256, 256, 2, 4, 4><<<1024, blk, 0, stream>>>(
        Wb + 98304, bf, y3, xT, mask, part + 8192, go, bno, y2, part + 12288, 12);

    // final: out = (x + act3(y3)) + act4(y4)
    final_kernel<<<kP / 32, blk, 0, stream>>>(
        xT, y3, y2, part + 8192, go, bno, part + 12288, gf, bnf, mask, out);
}

// Round 5
// 389.192 us; speedup vs baseline: 1.0279x; 1.0279x over previous
//
#include <hip/hip_runtime.h>
#include <hip/hip_bf16.h>

typedef __attribute__((ext_vector_type(8))) __bf16 bf16x8;
typedef __attribute__((ext_vector_type(4))) float floatx4;
typedef __attribute__((ext_vector_type(8))) unsigned short ushort8;

namespace {
constexpr int kC  = 256;
constexpr int kNV = 1024 * 12;        // 12288
constexpr int kP  = 8 * kNV;          // 98304 positions
constexpr float kEps = 1e-5f;

// ws layout in float units
constexpr size_t OFF_PART   = 2048;                      // 4 stages x 8 buckets x 512
constexpr size_t OFF_WB     = 2048 + 16384;              // packed bf16 weights
constexpr size_t OFF_XT     = OFF_WB + 81920;            // x transposed [P][256] bf16 (pristine)
constexpr size_t OFF_Y1     = OFF_XT + (size_t)kP * 256 / 2;
constexpr size_t OFF_Y2     = OFF_Y1 + (size_t)kP * 64 / 2;   // [P][256] bf16 (also y4)
constexpr size_t OFF_Y3     = OFF_Y2 + (size_t)kP * 256 / 2;
} // namespace

__device__ __forceinline__ unsigned short f2bf(float f) {
    unsigned int u = __builtin_bit_cast(unsigned int, f);
    u += 0x7FFFu + ((u >> 16) & 1u);
    return (unsigned short)(u >> 16);
}
__device__ __forceinline__ float bf2f(unsigned short h) {
    unsigned int u = ((unsigned int)h) << 16;
    return __builtin_bit_cast(float, u);
}
// pack two f32 -> two bf16 (RTNE) in one VALU op
__device__ __forceinline__ unsigned int f2bf2(float lo, float hi) {
    unsigned int r;
    asm("v_cvt_pk_bf16_f32 %0, %1, %2" : "=v"(r) : "v"(lo), "v"(hi));
    return r;
}

// Pack the 4 weight matrices to bf16 in MFMA-fragment order:
// dst[base + (k/32)*(M*32) + m*32 + (k%32)]
__global__ void convw_kernel(const float* __restrict__ We, const float* __restrict__ Wa,
                             const float* __restrict__ Wo, const float* __restrict__ Wf,
                             unsigned short* __restrict__ dst)
{
    const int f = (blockIdx.x * 256 + threadIdx.x) * 4;
    const float* src; int off, M, K, base;
    if (f < 16384)      { src = We;            off = f;         M = 64;  K = 256; base = 0; }
    else if (f < 32768) { src = Wa + 512 * 64; off = f - 16384; M = 256; K = 64;  base = 16384; }
    else if (f < 98304) { src = Wo;            off = f - 32768; M = 256; K = 256; base = 32768; }
    else                { src = Wf;            off = f - 98304; M = 256; K = 256; base = 98304; }
    const int m = off / K, k = off - m * K;
    const float4 v = *(const float4*)&src[off];
    ushort4 o; o.x = f2bf(v.x); o.y = f2bf(v.y); o.z = f2bf(v.z); o.w = f2bf(v.w);
    *(ushort4*)&dst[base + (k >> 5) * (M * 32) + m * 32 + (k & 31)] = o;
}

// x [B,256,NV] fp32 channel-major -> xT [P][256] bf16 position-major
__global__ __launch_bounds__(256) void transpose_kernel(
    const float* __restrict__ x, unsigned short* __restrict__ xT)
{
    __shared__ float T[64][65];
    const int p0 = blockIdx.x * 64;
    const int c0 = blockIdx.y * 64;
    const int b  = p0 / kNV;
    const int q0 = p0 - b * kNV;
    const int t  = threadIdx.x;

    const int cl = t >> 2;
    const int pq = (t & 3) * 16;
    const float* src = &x[(size_t)(b * kC + c0 + cl) * kNV + q0 + pq];
    #pragma unroll
    for (int i = 0; i < 4; ++i) {
        const float4 v = *(const float4*)&src[i * 4];
        T[cl][pq + i * 4 + 0] = v.x;
        T[cl][pq + i * 4 + 1] = v.y;
        T[cl][pq + i * 4 + 2] = v.z;
        T[cl][pq + i * 4 + 3] = v.w;
    }
    __syncthreads();
    const int pr = t >> 2;
    const int cb = (t & 3) * 16;
    #pragma unroll
    for (int i = 0; i < 2; ++i) {
        ushort8 o;
        #pragma unroll
        for (int j = 0; j < 8; ++j) o[j] = f2bf(T[cb + i * 8 + j][pr]);
        *(ushort8*)&xT[(size_t)(p0 + pr) * 256 + c0 + cb + i * 8] = o;
    }
}

template<int MODE>
__device__ __forceinline__ ushort8 xform(ushort8 y8, ushort8 x8, float mp,
                                         const float* __restrict__ actA,
                                         const float* __restrict__ actB, int kk)
{
    if constexpr (MODE == 0) {
        return y8;
    } else {
        const float4 a0 = *(const float4*)&actA[kk];
        const float4 a1 = *(const float4*)&actA[kk + 4];
        const float4 b0 = *(const float4*)&actB[kk];
        const float4 b1 = *(const float4*)&actB[kk + 4];
        const float aa[8] = {a0.x, a0.y, a0.z, a0.w, a1.x, a1.y, a1.z, a1.w};
        const float bb[8] = {b0.x, b0.y, b0.z, b0.w, b1.x, b1.y, b1.z, b1.w};
        float v[8];
        #pragma unroll
        for (int j = 0; j < 8; ++j) {
            float t = mp * fmaxf(fmaf(aa[j], bf2f(y8[j]), bb[j]), 0.f);
            if constexpr (MODE == 2) t += bf2f(x8[j]);
            v[j] = t;
        }
        uint4 u;
        u.x = f2bf2(v[0], v[1]); u.y = f2bf2(v[2], v[3]);
        u.z = f2bf2(v[4], v[5]); u.w = f2bf2(v[6], v[7]);
        return __builtin_bit_cast(ushort8, u);
    }
}

// A-stationary GEMM. Block = 4 waves; wave owns BM/4 output channels with full-K A
// fragments in REGISTERS. B streams as 32-position slabs through a double-buffered
// LDS tile; one barrier per slab.
// SIBS sibling blocks split the MTOT output channels (BM=MTOT/SIBS each) for the same
// slab range; XCD-grouping swizzle (round-robin: bid%8 -> XCD) co-locates siblings on
// one XCD so the shared B-stream is HBM-read once, sibling reads hit that XCD's L2.
// DS-pipe diet (this round): BN stats accumulate in REGISTERS across all slabs and
// flush once at kernel end (removes the per-slab __shfl_xor storm that saturated the
// CU's single LDS pipe); bias hoisted to registers; bf16 packing via v_cvt_pk_bf16_f32.
// MODE 0: B = raw bf16. MODE 1: B = mask*relu(a*y+b). MODE 2: MODE1 + XT residual
// (XT read-only; x1 is NOT materialized).
template<int BM, int MTOT, int K, int MODE, int SIBS, int MINW>
__global__ __launch_bounds__(256, MINW) void gemm_kernel(
    const unsigned short* __restrict__ Apk, const float* __restrict__ bias,
    const unsigned short* __restrict__ Yprev, const unsigned short* __restrict__ XT,
    const float* __restrict__ mask,
    const float* __restrict__ pPrev, const float* __restrict__ gPrev,
    const float* __restrict__ btPrev,
    unsigned short* __restrict__ Yout, float* __restrict__ partial, int slabsPerBlock)
{
    constexpr int LD = 264;              // padded row stride (shorts): 2-way banks max
    constexpr int NT = K / 32;
    constexpr int FM = BM / 64;          // channels-per-wave / 16
    constexpr int FP = 2;                // 32 positions per slab
    constexpr int CH = K / 64;           // ushort8 chunks per thread per stream
    __shared__ unsigned short Bs[2][32 * LD];
    __shared__ float ActA[256];
    __shared__ float ActB[256];

    const int tid  = threadIdx.x;
    const int w    = tid >> 6, lane = tid & 63, quad = lane >> 4, lt = lane & 15;
    const int mBase = w * 16 * FM;

    // ---- block -> (group, sibling). Round-robin dispatch: bid%8 -> XCD bid%8;
    // siblings are 8 apart in bid -> same XCD, adjacent in dispatch order.
    int groupId, sib;
    if constexpr (SIBS > 1) {
        const int x = blockIdx.x & 7;
        const int s = blockIdx.x >> 3;
        const int perX = (int)(gridDim.x >> 3) / SIBS;
        sib = s % SIBS;
        groupId = x * perX + s / SIBS;
    } else {
        groupId = blockIdx.x; sib = 0;
    }
    const int chOff = sib * BM;
    const int slab0 = groupId * slabsPerBlock;

    // ---- fold previous stage's BN into per-channel affine (finalize folded in) ----
    if constexpr (MODE != 0) {
        if (tid < K) {
            float s = 0.f, s2 = 0.f;
            #pragma unroll
            for (int k = 0; k < 8; ++k) {
                s  += pPrev[k * 512 + tid];
                s2 += pPrev[k * 512 + 256 + tid];
            }
            const float mu  = s * (1.f / kP);
            const float var = s2 * (1.f / kP) - mu * mu;
            const float A   = rsqrtf(var + kEps) * gPrev[tid];
            ActA[tid] = A;
            ActB[tid] = fmaf(-mu, A, btPrev[tid]);
        }
        __syncthreads();
    }

    // ---- A fragments: full K for this block's channel slice, in registers ----
    ushort8 Areg[NT][FM];
    #pragma unroll
    for (int t = 0; t < NT; ++t)
        #pragma unroll
        for (int fm = 0; fm < FM; ++fm)
            Areg[t][fm] = *(const ushort8*)&Apk[(size_t)(t * MTOT + chOff + mBase + fm * 16 + lt) * 32 + quad * 8];

    // ---- bias hoisted to registers (invariant across slabs) ----
    float biR[FM][4];
    #pragma unroll
    for (int fm = 0; fm < FM; ++fm) {
        const float4 b4 = *(const float4*)&bias[chOff + mBase + fm * 16 + quad * 4];
        biR[fm][0] = b4.x; biR[fm][1] = b4.y; biR[fm][2] = b4.z; biR[fm][3] = b4.w;
    }

    // ---- BN stats accumulate in registers across all slabs ----
    float aS[FM][4], aQ[FM][4];
    #pragma unroll
    for (int fm = 0; fm < FM; ++fm)
        #pragma unroll
        for (int i = 0; i < 4; ++i) { aS[fm][i] = 0.f; aQ[fm][i] = 0.f; }

    const int spb = slabsPerBlock;

    // ---- prologue: stage slab 0 into Bs[0] ----
    {
        const int pBase = slab0 * 32;
        #pragma unroll
        for (int i = 0; i < CH; ++i) {
            const int c = tid + i * 256;
            const int p = c / (K / 8);
            const int kq = (c % (K / 8)) * 8;
            const ushort8 y8 = *(const ushort8*)&Yprev[(size_t)(pBase + p) * K + kq];
            ushort8 o;
            if constexpr (MODE == 0) o = y8;
            else {
                ushort8 x8{};
                if constexpr (MODE == 2) x8 = *(const ushort8*)&XT[(size_t)(pBase + p) * K + kq];
                o = xform<MODE>(y8, x8, mask[pBase + p], ActA, ActB, kq);
            }
            *(ushort8*)&Bs[0][p * LD + kq] = o;
        }
    }
    __syncthreads();

    for (int s = 0; s < spb; ++s) {
        const int pBase = (slab0 + s) * 32;
        const bool hasNext = (s + 1 < spb);

        // ---- prefetch next slab's streams into registers (latency covered by MFMAs) ----
        ushort8 py[CH];
        ushort8 px[(MODE == 2) ? CH : 1];
        if (hasNext) {
            const int pN = (slab0 + s + 1) * 32;
            #pragma unroll
            for (int i = 0; i < CH; ++i) {
                const int c = tid + i * 256;
                const int p = c / (K / 8);
                const int kq = (c % (K / 8)) * 8;
                py[i] = *(const ushort8*)&Yprev[(size_t)(pN + p) * K + kq];
                if constexpr (MODE == 2)
                    px[i] = *(const ushort8*)&XT[(size_t)(pN + p) * K + kq];
            }
        }

        // ---- MFMA over current slab: LDS-only inner loop ----
        floatx4 acc[FM][FP];
        #pragma unroll
        for (int fm = 0; fm < FM; ++fm)
            #pragma unroll
            for (int fp = 0; fp < FP; ++fp) acc[fm][fp] = (floatx4)0.f;

        const unsigned short* bs = &Bs[s & 1][0];
        #pragma unroll
        for (int t = 0; t < NT; ++t) {
            bf16x8 bF[FP];
            #pragma unroll
            for (int fp = 0; fp < FP; ++fp)
                bF[fp] = *(const bf16x8*)&bs[(fp * 16 + lt) * LD + t * 32 + quad * 8];
            #pragma unroll
            for (int fm = 0; fm < FM; ++fm) {
                const bf16x8 aF = __builtin_bit_cast(bf16x8, Areg[t][fm]);
                #pragma unroll
                for (int fp = 0; fp < FP; ++fp)
                    acc[fm][fp] = __builtin_amdgcn_mfma_f32_16x16x32_bf16(aF, bF[fp], acc[fm][fp], 0, 0, 0);
            }
        }

        // ---- epilogue: bias + mask, packed bf16 store, stats into registers ----
        float mpv[FP];
        #pragma unroll
        for (int fp = 0; fp < FP; ++fp) mpv[fp] = mask[pBase + fp * 16 + lt];

        #pragma unroll
        for (int fm = 0; fm < FM; ++fm) {
            #pragma unroll
            for (int fp = 0; fp < FP; ++fp) {
                const int pG = pBase + fp * 16 + lt;
                float vv[4];
                #pragma unroll
                for (int i = 0; i < 4; ++i) {
                    const float v = (acc[fm][fp][i] + biR[fm][i]) * mpv[fp];
                    vv[i] = v; aS[fm][i] += v; aQ[fm][i] += v * v;
                }
                uint2 o; o.x = f2bf2(vv[0], vv[1]); o.y = f2bf2(vv[2], vv[3]);
                *(uint2*)&Yout[(size_t)pG * MTOT + chOff + mBase + fm * 16 + quad * 4] = o;
            }
        }

        // ---- xform prefetched data, write other LDS buffer ----
        if (hasNext) {
            const int pN = (slab0 + s + 1) * 32;
            unsigned short* bn = &Bs[(s + 1) & 1][0];
            #pragma unroll
            for (int i = 0; i < CH; ++i) {
                const int c = tid + i * 256;
                const int p = c / (K / 8);
                const int kq = (c % (K / 8)) * 8;
                ushort8 o;
                if constexpr (MODE == 0) o = py[i];
                else {
                    ushort8 x8{};
                    if constexpr (MODE == 2) x8 = px[i];
                    o = xform<MODE>(py[i], x8, mask[pN + p], ActA, ActB, kq);
                }
                *(ushort8*)&bn[p * LD + kq] = o;
            }
        }
        __syncthreads();
    }

    // ---- flush stats ONCE: butterfly over the 16-lane group + owner-lane atomics ----
    #pragma unroll
    for (int fm = 0; fm < FM; ++fm)
        #pragma unroll
        for (int i = 0; i < 4; ++i) {
            #pragma unroll
            for (int off = 1; off < 16; off <<= 1) {
                aS[fm][i] += __shfl_xor(aS[fm][i], off);
                aQ[fm][i] += __shfl_xor(aQ[fm][i], off);
            }
        }
    if (lt == 0) {
        float* pb = partial + (size_t)(blockIdx.x & 7) * 512;
        #pragma unroll
        for (int fm = 0; fm < FM; ++fm)
            #pragma unroll
            for (int i = 0; i < 4; ++i) {
                const int ch = chOff + mBase + fm * 16 + quad * 4 + i;  // unique owner
                atomicAdd(&pb[ch], aS[fm][i]);
                atomicAdd(&pb[256 + ch], aQ[fm][i]);
            }
    }
}

// out[c][q] = x1 + act4(y4), with x1 = x + act3(y3) recomputed on the fly.
// Both act3 and act4 affines computed in-prologue from the part buckets.
__global__ __launch_bounds__(256) void final_kernel(
    const unsigned short* __restrict__ xT, const unsigned short* __restrict__ y3,
    const unsigned short* __restrict__ y4,
    const float* __restrict__ p3, const float* __restrict__ g3, const float* __restrict__ bt3,
    const float* __restrict__ p4, const float* __restrict__ g4, const float* __restrict__ bt4,
    const float* __restrict__ mask, float* __restrict__ out)
{
    constexpr int TL = 264;
    __shared__ unsigned short TX[32 * TL];   // x1 (bf16)
    __shared__ unsigned short T4[32 * TL];   // y4 raw
    __shared__ float PA3[256], PB3[256], PA4[256], PB4[256];
    const int p0 = blockIdx.x * 32;
    const int b  = p0 / kNV;
    const int q0 = p0 - b * kNV;

    {
        const int m = threadIdx.x;
        float s3 = 0.f, q3 = 0.f, s4 = 0.f, q4 = 0.f;
        #pragma unroll
        for (int k = 0; k < 8; ++k) {
            s3 += p3[k * 512 + m]; q3 += p3[k * 512 + 256 + m];
            s4 += p4[k * 512 + m]; q4 += p4[k * 512 + 256 + m];
        }
        const float mu3 = s3 * (1.f / kP);
        const float A3  = rsqrtf(q3 * (1.f / kP) - mu3 * mu3 + kEps) * g3[m];
        PA3[m] = A3; PB3[m] = fmaf(-mu3, A3, bt3[m]);
        const float mu4 = s4 * (1.f / kP);
        const float A4  = rsqrtf(q4 * (1.f / kP) - mu4 * mu4 + kEps) * g4[m];
        PA4[m] = A4; PB4[m] = fmaf(-mu4, A4, bt4[m]);
    }
    __syncthreads();

    #pragma unroll
    for (int i = 0; i < 4; ++i) {
        const int idx = threadIdx.x + i * 256;
        const int p = idx >> 5, c0 = (idx & 31) * 8;
        const ushort8 x8  = *(const ushort8*)&xT[(size_t)(p0 + p) * 256 + c0];
        const ushort8 y38 = *(const ushort8*)&y3[(size_t)(p0 + p) * 256 + c0];
        const ushort8 y48 = *(const ushort8*)&y4[(size_t)(p0 + p) * 256 + c0];
        const float mp = mask[p0 + p];
        ushort8 o;
        #pragma unroll
        for (int j = 0; j < 8; ++j) {
            const int c = c0 + j;
            const float x1 = bf2f(x8[j]) + mp * fmaxf(fmaf(PA3[c], bf2f(y38[j]), PB3[c]), 0.f);
            o[j] = f2bf(x1);
        }
        *(ushort8*)&TX[p * TL + c0] = o;
        *(ushort8*)&T4[p * TL + c0] = y48;
    }
    __syncthreads();

    const int qv = (threadIdx.x & 15) * 2;
    const int cb = threadIdx.x >> 4;
    const float m0v = mask[p0 + qv], m1v = mask[p0 + qv + 1];
    #pragma unroll
    for (int j = 0; j < 16; ++j) {
        const int c = cb + j * 16;
        const float a4 = PA4[c], b4 = PB4[c];
        const size_t ro = (size_t)(b * kC + c) * kNV + q0 + qv;
        float2 o;
        o.x = bf2f(TX[qv * TL + c])       + m0v * fmaxf(fmaf(a4, bf2f(T4[qv * TL + c]), b4), 0.f);
        o.y = bf2f(TX[(qv + 1) * TL + c]) + m1v * fmaxf(fmaf(a4, bf2f(T4[(qv + 1) * TL + c]), b4), 0.f);
        *(float2*)&out[ro] = o;
    }
}

extern "C" void kernel_launch(void* const* d_in, const int* in_sizes, int n_in,
                              void* d_out, int out_size, void* d_ws, size_t ws_size,
                              hipStream_t stream)
{
    const float* x    = (const float*)d_in[0];
    const float* mask = (const float*)d_in[1];
    const float* We   = (const float*)d_in[2];
    const float* be   = (const float*)d_in[3];
    const float* ge   = (const float*)d_in[4];
    const float* bne  = (const float*)d_in[5];
    const float* Wa   = (const float*)d_in[6];
    const float* ba   = (const float*)d_in[7];
    const float* ga   = (const float*)d_in[8];
    const float* bna  = (const float*)d_in[9];
    const float* Wo   = (const float*)d_in[10];
    const float* bo   = (const float*)d_in[11];
    const float* go   = (const float*)d_in[12];
    const float* bno  = (const float*)d_in[13];
    const float* Wf   = (const float*)d_in[14];
    const float* bf   = (const float*)d_in[15];
    const float* gf   = (const float*)d_in[16];
    const float* bnf  = (const float*)d_in[17];
    float* out = (float*)d_out;
    float* ws  = (float*)d_ws;

    float* part = ws + OFF_PART;
    unsigned short* Wb = (unsigned short*)(ws + OFF_WB);
    unsigned short* xT = (unsigned short*)(ws + OFF_XT);
    unsigned short* y1 = (unsigned short*)(ws + OFF_Y1);
    unsigned short* y2 = (unsigned short*)(ws + OFF_Y2);   // later reused as y4
    unsigned short* y3 = (unsigned short*)(ws + OFF_Y3);

    hipMemsetAsync(part, 0, 16384 * sizeof(float), stream);
    convw_kernel<<<160, 256, 0, stream>>>(We, Wa, Wo, Wf, Wb);
    transpose_kernel<<<dim3(kP / 64, 4), 256, 0, stream>>>(x, xT);

    const dim3 blk(256);

    // stage 1: y1 = mask*(We @ x + be)  [P][64]
    gemm_kernel<64, 64, 256, 0, 1, 4><<<1024, blk, 0, stream>>>(
        Wb, be, xT, nullptr, mask, nullptr, nullptr, nullptr, y1, part, 3);

    // stage 2: y2 = mask*(Wa_v @ act1(y1) + ba_v)  [P][256]  2 siblings, 4 blk/CU
    gemm_kernel<128, 256, 64, 1, 2, 4><<<1024, blk, 0, stream>>>(
        Wb + 16384, ba + 512, y1, nullptr, mask, part, ge, bne, y2, part + 4096, 6);

    // stage 3: y3 = mask*(Wo @ act2(y2) + bo)   2 siblings, FM=2
    gemm_kernel<128, 256, 256, 1, 2, 3><<<768, blk, 0, stream>>>(
        Wb + 32768, bo, y2, nullptr, mask, part + 4096, ga + 512, bna + 512, y3, part + 8192, 8);

    // stage 4: y4 = mask*(Wf @ (x + act3(y3)) + bf)   XT read-only
    gemm_kernel<128, 256, 256, 2, 2, 3><<<768, blk, 0, stream>>>(
        Wb + 98304, bf, y3, xT, mask, part + 8192, go, bno, y2, part + 12288, 8);

    // final: out = (x + act3(y3)) + act4(y4)
    final_kernel<<<kP / 32, blk, 0, stream>>>(
        xT, y3, y2, part + 8192, go, bno, part + 12288, gf, bnf, mask, out);
}

// Round 6
// 381.029 us; speedup vs baseline: 1.0499x; 1.0214x over previous
//
#include <hip/hip_runtime.h>
#include <hip/hip_bf16.h>

typedef __attribute__((ext_vector_type(8))) __bf16 bf16x8;
typedef __attribute__((ext_vector_type(4))) float floatx4;
typedef __attribute__((ext_vector_type(8))) unsigned short ushort8;

namespace {
constexpr int kC  = 256;
constexpr int kNV = 1024 * 12;        // 12288
constexpr int kP  = 8 * kNV;          // 98304 positions
constexpr float kEps = 1e-5f;

// ws layout in float units
constexpr size_t OFF_PART   = 2048;                      // 4 stages x 8 buckets x 512
constexpr size_t OFF_WB     = 2048 + 16384;              // packed bf16 weights
constexpr size_t OFF_XT     = OFF_WB + 81920;            // x transposed [P][256] bf16 (pristine)
constexpr size_t OFF_Y1     = OFF_XT + (size_t)kP * 256 / 2;
constexpr size_t OFF_Y2     = OFF_Y1 + (size_t)kP * 64 / 2;   // [P][256] bf16 (also y4)
constexpr size_t OFF_Y3     = OFF_Y2 + (size_t)kP * 256 / 2;
} // namespace

__device__ __forceinline__ unsigned short f2bf(float f) {
    unsigned int u = __builtin_bit_cast(unsigned int, f);
    u += 0x7FFFu + ((u >> 16) & 1u);
    return (unsigned short)(u >> 16);
}
__device__ __forceinline__ float bf2f(unsigned short h) {
    unsigned int u = ((unsigned int)h) << 16;
    return __builtin_bit_cast(float, u);
}
// pack two f32 -> two bf16 (RTNE) in one VALU op
__device__ __forceinline__ unsigned int f2bf2(float lo, float hi) {
    unsigned int r;
    asm("v_cvt_pk_bf16_f32 %0, %1, %2" : "=v"(r) : "v"(lo), "v"(hi));
    return r;
}

// phase barrier WITHOUT vmcnt drain: LDS visibility only (m194/m201 pattern).
// Global loads issued before it stay in flight across the barrier; their
// consumers get compiler-inserted vmcnt waits at first use.
__device__ __forceinline__ void phase_barrier() {
    asm volatile("s_waitcnt lgkmcnt(0)" ::: "memory");
    __builtin_amdgcn_s_barrier();
    asm volatile("" ::: "memory");
}

// Pack the 4 weight matrices to bf16 in MFMA-fragment order:
// dst[base + (k/32)*(M*32) + m*32 + (k%32)]
__global__ void convw_kernel(const float* __restrict__ We, const float* __restrict__ Wa,
                             const float* __restrict__ Wo, const float* __restrict__ Wf,
                             unsigned short* __restrict__ dst)
{
    const int f = (blockIdx.x * 256 + threadIdx.x) * 4;
    const float* src; int off, M, K, base;
    if (f < 16384)      { src = We;            off = f;         M = 64;  K = 256; base = 0; }
    else if (f < 32768) { src = Wa + 512 * 64; off = f - 16384; M = 256; K = 64;  base = 16384; }
    else if (f < 98304) { src = Wo;            off = f - 32768; M = 256; K = 256; base = 32768; }
    else                { src = Wf;            off = f - 98304; M = 256; K = 256; base = 98304; }
    const int m = off / K, k = off - m * K;
    const float4 v = *(const float4*)&src[off];
    ushort4 o; o.x = f2bf(v.x); o.y = f2bf(v.y); o.z = f2bf(v.z); o.w = f2bf(v.w);
    *(ushort4*)&dst[base + (k >> 5) * (M * 32) + m * 32 + (k & 31)] = o;
}

// x [B,256,NV] fp32 channel-major -> xT [P][256] bf16 position-major
__global__ __launch_bounds__(256) void transpose_kernel(
    const float* __restrict__ x, unsigned short* __restrict__ xT)
{
    __shared__ float T[64][65];
    const int p0 = blockIdx.x * 64;
    const int c0 = blockIdx.y * 64;
    const int b  = p0 / kNV;
    const int q0 = p0 - b * kNV;
    const int t  = threadIdx.x;

    const int cl = t >> 2;
    const int pq = (t & 3) * 16;
    const float* src = &x[(size_t)(b * kC + c0 + cl) * kNV + q0 + pq];
    #pragma unroll
    for (int i = 0; i < 4; ++i) {
        const float4 v = *(const float4*)&src[i * 4];
        T[cl][pq + i * 4 + 0] = v.x;
        T[cl][pq + i * 4 + 1] = v.y;
        T[cl][pq + i * 4 + 2] = v.z;
        T[cl][pq + i * 4 + 3] = v.w;
    }
    __syncthreads();
    const int pr = t >> 2;
    const int cb = (t & 3) * 16;
    #pragma unroll
    for (int i = 0; i < 2; ++i) {
        ushort8 o;
        #pragma unroll
        for (int j = 0; j < 8; ++j) o[j] = f2bf(T[cb + i * 8 + j][pr]);
        *(ushort8*)&xT[(size_t)(p0 + pr) * 256 + c0 + cb + i * 8] = o;
    }
}

template<int MODE>
__device__ __forceinline__ ushort8 xform(ushort8 y8, ushort8 x8, float mp,
                                         const float* __restrict__ actA,
                                         const float* __restrict__ actB, int kk)
{
    if constexpr (MODE == 0) {
        return y8;
    } else {
        const float4 a0 = *(const float4*)&actA[kk];
        const float4 a1 = *(const float4*)&actA[kk + 4];
        const float4 b0 = *(const float4*)&actB[kk];
        const float4 b1 = *(const float4*)&actB[kk + 4];
        const float aa[8] = {a0.x, a0.y, a0.z, a0.w, a1.x, a1.y, a1.z, a1.w};
        const float bb[8] = {b0.x, b0.y, b0.z, b0.w, b1.x, b1.y, b1.z, b1.w};
        float v[8];
        #pragma unroll
        for (int j = 0; j < 8; ++j) {
            float t = mp * fmaxf(fmaf(aa[j], bf2f(y8[j]), bb[j]), 0.f);
            if constexpr (MODE == 2) t += bf2f(x8[j]);
            v[j] = t;
        }
        uint4 u;
        u.x = f2bf2(v[0], v[1]); u.y = f2bf2(v[2], v[3]);
        u.z = f2bf2(v[4], v[5]); u.w = f2bf2(v[6], v[7]);
        return __builtin_bit_cast(ushort8, u);
    }
}

// A-stationary GEMM with a 3-buffer counted-wait pipeline.
// Block = 4 waves; wave owns BM/4 output channels, full-K A frags in registers.
// SIBS sibling blocks split MTOT channels for the same slab range; XCD-grouping
// swizzle co-locates siblings on one XCD (shared B-stream deduped through L2).
// Pipeline (slab s -> buffer s%3): in STEP(s) we issue global loads for slab s+2
// and masks for s+1, MFMA buffer s, xform the (long-landed) s+1 data into buffer
// (s+1)%3, store slab-s epilogue, then a RAW s_barrier with lgkmcnt(0) only --
// no vmcnt drain, so prefetch loads stay in flight across the barrier (the
// __syncthreads vmcnt(0) drain was the per-phase memory-idle tail).
// BN stats accumulate in registers; flush once via owner-lane atomics.
// MODE 0: B = raw bf16. MODE 1: B = mask*relu(a*y+b). MODE 2: MODE1 + XT residual.
// slabsPerBlock must be EVEN (pair-unrolled register-set swap).
template<int BM, int MTOT, int K, int MODE, int SIBS, int MINW>
__global__ __launch_bounds__(256, MINW) void gemm_kernel(
    const unsigned short* __restrict__ Apk, const float* __restrict__ bias,
    const unsigned short* __restrict__ Yprev, const unsigned short* __restrict__ XT,
    const float* __restrict__ mask,
    const float* __restrict__ pPrev, const float* __restrict__ gPrev,
    const float* __restrict__ btPrev,
    unsigned short* __restrict__ Yout, float* __restrict__ partial, int slabsPerBlock)
{
    constexpr int LD = K + 8;            // padded row stride (shorts): 2-way banks max
    constexpr int NT = K / 32;
    constexpr int FM = BM / 64;          // channels-per-wave / 16
    constexpr int FP = 2;                // 32 positions per slab
    constexpr int CH = K / 64;           // ushort8 chunks per thread per stream
    constexpr int XH = (MODE == 2) ? CH : 1;
    __shared__ unsigned short Bs[3][32 * LD];
    __shared__ float ActA[256];
    __shared__ float ActB[256];

    const int tid  = threadIdx.x;
    const int w    = tid >> 6, lane = tid & 63, quad = lane >> 4, lt = lane & 15;
    const int mBase = w * 16 * FM;

    // ---- block -> (group, sibling). Round-robin dispatch: bid%8 -> XCD bid%8;
    // siblings are 8 apart in bid -> same XCD, adjacent in dispatch order.
    int groupId, sib;
    if constexpr (SIBS > 1) {
        const int x = blockIdx.x & 7;
        const int s = blockIdx.x >> 3;
        const int perX = (int)(gridDim.x >> 3) / SIBS;
        sib = s % SIBS;
        groupId = x * perX + s / SIBS;
    } else {
        groupId = blockIdx.x; sib = 0;
    }
    const int chOff = sib * BM;
    const int spb   = slabsPerBlock;
    const int slab0 = groupId * spb;

    // ---- fold previous stage's BN into per-channel affine (finalize folded in) ----
    if constexpr (MODE != 0) {
        if (tid < K) {
            float s = 0.f, s2 = 0.f;
            #pragma unroll
            for (int k = 0; k < 8; ++k) {
                s  += pPrev[k * 512 + tid];
                s2 += pPrev[k * 512 + 256 + tid];
            }
            const float mu  = s * (1.f / kP);
            const float var = s2 * (1.f / kP) - mu * mu;
            const float A   = rsqrtf(var + kEps) * gPrev[tid];
            ActA[tid] = A;
            ActB[tid] = fmaf(-mu, A, btPrev[tid]);
        }
        __syncthreads();
    }

    // ---- A fragments: full K for this block's channel slice, in registers ----
    ushort8 Areg[NT][FM];
    #pragma unroll
    for (int t = 0; t < NT; ++t)
        #pragma unroll
        for (int fm = 0; fm < FM; ++fm)
            Areg[t][fm] = *(const ushort8*)&Apk[(size_t)(t * MTOT + chOff + mBase + fm * 16 + lt) * 32 + quad * 8];

    // ---- bias hoisted to registers (invariant across slabs) ----
    float biR[FM][4];
    #pragma unroll
    for (int fm = 0; fm < FM; ++fm) {
        const float4 b4 = *(const float4*)&bias[chOff + mBase + fm * 16 + quad * 4];
        biR[fm][0] = b4.x; biR[fm][1] = b4.y; biR[fm][2] = b4.z; biR[fm][3] = b4.w;
    }

    // ---- BN stats accumulate in registers across all slabs ----
    float aS[FM][4], aQ[FM][4];
    #pragma unroll
    for (int fm = 0; fm < FM; ++fm)
        #pragma unroll
        for (int i = 0; i < 4; ++i) { aS[fm][i] = 0.f; aQ[fm][i] = 0.f; }

    // ---- two prefetch register sets ----
    ushort8 pyA[CH], pyB[CH];
    ushort8 pxA[XH], pxB[XH];
    float   mxA[CH], mxB[CH];
    float   meA[FP], meB[FP];

    // ---- prologue: direct-stage slab 0 into Bs[0]; fill set A (me slab0, streams slab1) ----
    {
        const int pBase = slab0 * 32;
        #pragma unroll
        for (int i = 0; i < CH; ++i) {
            const int c = tid + i * 256;
            const int p = c / (K / 8);
            const int kq = (c % (K / 8)) * 8;
            const ushort8 y8 = *(const ushort8*)&Yprev[(size_t)(pBase + p) * K + kq];
            ushort8 o;
            if constexpr (MODE == 0) o = y8;
            else {
                ushort8 x8{};
                if constexpr (MODE == 2) x8 = *(const ushort8*)&XT[(size_t)(pBase + p) * K + kq];
                o = xform<MODE>(y8, x8, mask[pBase + p], ActA, ActB, kq);
            }
            *(ushort8*)&Bs[0][p * LD + kq] = o;
        }
        #pragma unroll
        for (int fp = 0; fp < FP; ++fp) meA[fp] = mask[pBase + fp * 16 + lt];
        const int pN = (slab0 + 1) * 32;     // spb >= 2 always
        #pragma unroll
        for (int i = 0; i < CH; ++i) {
            const int c = tid + i * 256;
            const int p = c / (K / 8);
            const int kq = (c % (K / 8)) * 8;
            pyA[i] = *(const ushort8*)&Yprev[(size_t)(pN + p) * K + kq];
            if constexpr (MODE == 2) pxA[i] = *(const ushort8*)&XT[(size_t)(pN + p) * K + kq];
            if constexpr (MODE != 0) mxA[i] = mask[pN + p];
        }
    }
    phase_barrier();

    // ---- one pipeline step: consume use-set (streams=slab s+1, me=slab s),
    //      fill fill-set (streams=slab s+2, me=slab s+1), MFMA buf[cur] ----
    auto stepf = [&](int s, int cur,
                     ushort8 (&uy)[CH], ushort8 (&ux)[XH], float (&umx)[CH], float (&ume)[FP],
                     ushort8 (&fy)[CH], ushort8 (&fx)[XH], float (&fmx)[CH], float (&fme)[FP]) {
        // ---- issue next prefetches FIRST (land during this+next phase) ----
        if (s + 1 < spb) {
            const int pE = (slab0 + s + 1) * 32;
            #pragma unroll
            for (int fp = 0; fp < FP; ++fp) fme[fp] = mask[pE + fp * 16 + lt];
        }
        if (s + 2 < spb) {
            const int pN = (slab0 + s + 2) * 32;
            #pragma unroll
            for (int i = 0; i < CH; ++i) {
                const int c = tid + i * 256;
                const int p = c / (K / 8);
                const int kq = (c % (K / 8)) * 8;
                fy[i] = *(const ushort8*)&Yprev[(size_t)(pN + p) * K + kq];
                if constexpr (MODE == 2) fx[i] = *(const ushort8*)&XT[(size_t)(pN + p) * K + kq];
                if constexpr (MODE != 0) fmx[i] = mask[pN + p];
            }
        }

        // ---- MFMA over current slab: LDS-only inner loop ----
        floatx4 acc[FM][FP];
        #pragma unroll
        for (int fm = 0; fm < FM; ++fm)
            #pragma unroll
            for (int fp = 0; fp < FP; ++fp) acc[fm][fp] = (floatx4)0.f;

        const unsigned short* bs = &Bs[cur][0];
        #pragma unroll
        for (int t = 0; t < NT; ++t) {
            bf16x8 bF[FP];
            #pragma unroll
            for (int fp = 0; fp < FP; ++fp)
                bF[fp] = *(const bf16x8*)&bs[(fp * 16 + lt) * LD + t * 32 + quad * 8];
            #pragma unroll
            for (int fm = 0; fm < FM; ++fm) {
                const bf16x8 aF = __builtin_bit_cast(bf16x8, Areg[t][fm]);
                #pragma unroll
                for (int fp = 0; fp < FP; ++fp)
                    acc[fm][fp] = __builtin_amdgcn_mfma_f32_16x16x32_bf16(aF, bF[fp], acc[fm][fp], 0, 0, 0);
            }
        }

        // ---- xform the long-landed use-set -> next buffer ----
        if (s + 1 < spb) {
            const int nb = (cur == 2) ? 0 : cur + 1;
            unsigned short* bn = &Bs[nb][0];
            #pragma unroll
            for (int i = 0; i < CH; ++i) {
                const int c = tid + i * 256;
                const int p = c / (K / 8);
                const int kq = (c % (K / 8)) * 8;
                ushort8 o;
                if constexpr (MODE == 0) o = uy[i];
                else {
                    ushort8 x8{};
                    if constexpr (MODE == 2) x8 = ux[i];
                    o = xform<MODE>(uy[i], x8, umx[i], ActA, ActB, kq);
                }
                *(ushort8*)&bn[p * LD + kq] = o;
            }
        }

        // ---- epilogue: bias + mask, packed bf16 store, stats into registers ----
        const int pBase = (slab0 + s) * 32;
        #pragma unroll
        for (int fm = 0; fm < FM; ++fm) {
            #pragma unroll
            for (int fp = 0; fp < FP; ++fp) {
                const int pG = pBase + fp * 16 + lt;
                float vv[4];
                #pragma unroll
                for (int i = 0; i < 4; ++i) {
                    const float v = (acc[fm][fp][i] + biR[fm][i]) * ume[fp];
                    vv[i] = v; aS[fm][i] += v; aQ[fm][i] += v * v;
                }
                uint2 o; o.x = f2bf2(vv[0], vv[1]); o.y = f2bf2(vv[2], vv[3]);
                *(uint2*)&Yout[(size_t)pG * MTOT + chOff + mBase + fm * 16 + quad * 4] = o;
            }
        }

        phase_barrier();
    };

    int cur = 0;
    for (int s = 0; s < spb; s += 2) {
        stepf(s,     cur, pyA, pxA, mxA, meA, pyB, pxB, mxB, meB);
        cur = (cur == 2) ? 0 : cur + 1;
        stepf(s + 1, cur, pyB, pxB, mxB, meB, pyA, pxA, mxA, meA);
        cur = (cur == 2) ? 0 : cur + 1;
    }

    // ---- flush stats ONCE: butterfly over the 16-lane group + owner-lane atomics ----
    #pragma unroll
    for (int fm = 0; fm < FM; ++fm)
        #pragma unroll
        for (int i = 0; i < 4; ++i) {
            #pragma unroll
            for (int off = 1; off < 16; off <<= 1) {
                aS[fm][i] += __shfl_xor(aS[fm][i], off);
                aQ[fm][i] += __shfl_xor(aQ[fm][i], off);
            }
        }
    if (lt == 0) {
        float* pb = partial + (size_t)(blockIdx.x & 7) * 512;
        #pragma unroll
        for (int fm = 0; fm < FM; ++fm)
            #pragma unroll
            for (int i = 0; i < 4; ++i) {
                const int ch = chOff + mBase + fm * 16 + quad * 4 + i;  // unique owner
                atomicAdd(&pb[ch], aS[fm][i]);
                atomicAdd(&pb[256 + ch], aQ[fm][i]);
            }
    }
}

// out[c][q] = x1 + act4(y4), with x1 = x + act3(y3) recomputed on the fly.
// Both act3 and act4 affines computed in-prologue from the part buckets.
__global__ __launch_bounds__(256) void final_kernel(
    const unsigned short* __restrict__ xT, const unsigned short* __restrict__ y3,
    const unsigned short* __restrict__ y4,
    const float* __restrict__ p3, const float* __restrict__ g3, const float* __restrict__ bt3,
    const float* __restrict__ p4, const float* __restrict__ g4, const float* __restrict__ bt4,
    const float* __restrict__ mask, float* __restrict__ out)
{
    constexpr int TL = 264;
    __shared__ unsigned short TX[32 * TL];   // x1 (bf16)
    __shared__ unsigned short T4[32 * TL];   // y4 raw
    __shared__ float PA3[256], PB3[256], PA4[256], PB4[256];
    const int p0 = blockIdx.x * 32;
    const int b  = p0 / kNV;
    const int q0 = p0 - b * kNV;

    {
        const int m = threadIdx.x;
        float s3 = 0.f, q3 = 0.f, s4 = 0.f, q4 = 0.f;
        #pragma unroll
        for (int k = 0; k < 8; ++k) {
            s3 += p3[k * 512 + m]; q3 += p3[k * 512 + 256 + m];
            s4 += p4[k * 512 + m]; q4 += p4[k * 512 + 256 + m];
        }
        const float mu3 = s3 * (1.f / kP);
        const float A3  = rsqrtf(q3 * (1.f / kP) - mu3 * mu3 + kEps) * g3[m];
        PA3[m] = A3; PB3[m] = fmaf(-mu3, A3, bt3[m]);
        const float mu4 = s4 * (1.f / kP);
        const float A4  = rsqrtf(q4 * (1.f / kP) - mu4 * mu4 + kEps) * g4[m];
        PA4[m] = A4; PB4[m] = fmaf(-mu4, A4, bt4[m]);
    }
    __syncthreads();

    #pragma unroll
    for (int i = 0; i < 4; ++i) {
        const int idx = threadIdx.x + i * 256;
        const int p = idx >> 5, c0 = (idx & 31) * 8;
        const ushort8 x8  = *(const ushort8*)&xT[(size_t)(p0 + p) * 256 + c0];
        const ushort8 y38 = *(const ushort8*)&y3[(size_t)(p0 + p) * 256 + c0];
        const ushort8 y48 = *(const ushort8*)&y4[(size_t)(p0 + p) * 256 + c0];
        const float mp = mask[p0 + p];
        ushort8 o;
        #pragma unroll
        for (int j = 0; j < 8; ++j) {
            const int c = c0 + j;
            const float x1 = bf2f(x8[j]) + mp * fmaxf(fmaf(PA3[c], bf2f(y38[j]), PB3[c]), 0.f);
            o[j] = f2bf(x1);
        }
        *(ushort8*)&TX[p * TL + c0] = o;
        *(ushort8*)&T4[p * TL + c0] = y48;
    }
    __syncthreads();

    const int qv = (threadIdx.x & 15) * 2;
    const int cb = threadIdx.x >> 4;
    const float m0v = mask[p0 + qv], m1v = mask[p0 + qv + 1];
    #pragma unroll
    for (int j = 0; j < 16; ++j) {
        const int c = cb + j * 16;
        const float a4 = PA4[c], b4 = PB4[c];
        const size_t ro = (size_t)(b * kC + c) * kNV + q0 + qv;
        float2 o;
        o.x = bf2f(TX[qv * TL + c])       + m0v * fmaxf(fmaf(a4, bf2f(T4[qv * TL + c]), b4), 0.f);
        o.y = bf2f(TX[(qv + 1) * TL + c]) + m1v * fmaxf(fmaf(a4, bf2f(T4[(qv + 1) * TL + c]), b4), 0.f);
        *(float2*)&out[ro] = o;
    }
}

extern "C" void kernel_launch(void* const* d_in, const int* in_sizes, int n_in,
                              void* d_out, int out_size, void* d_ws, size_t ws_size,
                              hipStream_t stream)
{
    const float* x    = (const float*)d_in[0];
    const float* mask = (const float*)d_in[1];
    const float* We   = (const float*)d_in[2];
    const float* be   = (const float*)d_in[3];
    const float* ge   = (const float*)d_in[4];
    const float* bne  = (const float*)d_in[5];
    const float* Wa   = (const float*)d_in[6];
    const float* ba   = (const float*)d_in[7];
    const float* ga   = (const float*)d_in[8];
    const float* bna  = (const float*)d_in[9];
    const float* Wo   = (const float*)d_in[10];
    const float* bo   = (const float*)d_in[11];
    const float* go   = (const float*)d_in[12];
    const float* bno  = (const float*)d_in[13];
    const float* Wf   = (const float*)d_in[14];
    const float* bf   = (const float*)d_in[15];
    const float* gf   = (const float*)d_in[16];
    const float* bnf  = (const float*)d_in[17];
    float* out = (float*)d_out;
    float* ws  = (float*)d_ws;

    float* part = ws + OFF_PART;
    unsigned short* Wb = (unsigned short*)(ws + OFF_WB);
    unsigned short* xT = (unsigned short*)(ws + OFF_XT);
    unsigned short* y1 = (unsigned short*)(ws + OFF_Y1);
    unsigned short* y2 = (unsigned short*)(ws + OFF_Y2);   // later reused as y4
    unsigned short* y3 = (unsigned short*)(ws + OFF_Y3);

    hipMemsetAsync(part, 0, 16384 * sizeof(float), stream);
    convw_kernel<<<160, 256, 0, stream>>>(We, Wa, Wo, Wf, Wb);
    transpose_kernel<<<dim3(kP / 64, 4), 256, 0, stream>>>(x, xT);

    const dim3 blk(256);

    // stage 1: y1 = mask*(We @ x + be)  [P][64]          spb=4 (even)
    gemm_kernel<64, 64, 256, 0, 1, 3><<<768, blk, 0, stream>>>(
        Wb, be, xT, nullptr, mask, nullptr, nullptr, nullptr, y1, part, 4);

    // stage 2: y2 = mask*(Wa_v @ act1(y1) + ba_v)  [P][256]  2 sibs, spb=6
    gemm_kernel<128, 256, 64, 1, 2, 4><<<1024, blk, 0, stream>>>(
        Wb + 16384, ba + 512, y1, nullptr, mask, part, ge, bne, y2, part + 4096, 6);

    // stage 3: y3 = mask*(Wo @ act2(y2) + bo)   4 sibs, FM=1, spb=16
    gemm_kernel<64, 256, 256, 1, 4, 3><<<768, blk, 0, stream>>>(
        Wb + 32768, bo, y2, nullptr, mask, part + 4096, ga + 512, bna + 512, y3, part + 8192, 16);

    // stage 4: y4 = mask*(Wf @ (x + act3(y3)) + bf)   XT read-only, 4 sibs, spb=16
    gemm_kernel<64, 256, 256, 2, 4, 3><<<768, blk, 0, stream>>>(
        Wb + 98304, bf, y3, xT, mask, part + 8192, go, bno, y2, part + 12288, 16);

    // final: out = (x + act3(y3)) + act4(y4)
    final_kernel<<<kP / 32, blk, 0, stream>>>(
        xT, y3, y2, part + 8192, go, bno, part + 12288, gf, bnf, mask, out);
}

// Round 7
// 358.741 us; speedup vs baseline: 1.1152x; 1.0621x over previous
//
#include <hip/hip_runtime.h>
#include <hip/hip_bf16.h>

typedef __attribute__((ext_vector_type(8))) __bf16 bf16x8;
typedef __attribute__((ext_vector_type(4))) float floatx4;
typedef __attribute__((ext_vector_type(8))) unsigned short ushort8;

namespace {
constexpr int kC  = 256;
constexpr int kNV = 1024 * 12;        // 12288
constexpr int kP  = 8 * kNV;          // 98304 positions
constexpr float kEps = 1e-5f;

// ws layout in float units
constexpr size_t OFF_PART   = 2048;                      // 4 stages x 8 buckets x 512
constexpr size_t OFF_WB     = 2048 + 16384;              // packed bf16 weights
constexpr size_t OFF_XT     = OFF_WB + 81920;            // x transposed [P][256] bf16 (pristine)
constexpr size_t OFF_Y1     = OFF_XT + (size_t)kP * 256 / 2;
constexpr size_t OFF_Y2     = OFF_Y1 + (size_t)kP * 64 / 2;   // [P][256] bf16 (also y4)
constexpr size_t OFF_Y3     = OFF_Y2 + (size_t)kP * 256 / 2;
} // namespace

__device__ __forceinline__ unsigned short f2bf(float f) {
    unsigned int u = __builtin_bit_cast(unsigned int, f);
    u += 0x7FFFu + ((u >> 16) & 1u);
    return (unsigned short)(u >> 16);
}
__device__ __forceinline__ float bf2f(unsigned short h) {
    unsigned int u = ((unsigned int)h) << 16;
    return __builtin_bit_cast(float, u);
}
// pack two f32 -> two bf16 (RTNE) in one VALU op
__device__ __forceinline__ unsigned int f2bf2(float lo, float hi) {
    unsigned int r;
    asm("v_cvt_pk_bf16_f32 %0, %1, %2" : "=v"(r) : "v"(lo), "v"(hi));
    return r;
}

// phase barrier WITHOUT vmcnt drain: LDS visibility only (m194/m201 pattern).
// Global loads/stores issued before it stay in flight across the barrier; load
// consumers get compiler-inserted vmcnt waits at first use.
__device__ __forceinline__ void phase_barrier() {
    asm volatile("s_waitcnt lgkmcnt(0)" ::: "memory");
    __builtin_amdgcn_s_barrier();
    asm volatile("" ::: "memory");
}

// Pack the 4 weight matrices to bf16 in MFMA-fragment order:
// dst[base + (k/32)*(M*32) + m*32 + (k%32)]
__global__ void convw_kernel(const float* __restrict__ We, const float* __restrict__ Wa,
                             const float* __restrict__ Wo, const float* __restrict__ Wf,
                             unsigned short* __restrict__ dst)
{
    const int f = (blockIdx.x * 256 + threadIdx.x) * 4;
    const float* src; int off, M, K, base;
    if (f < 16384)      { src = We;            off = f;         M = 64;  K = 256; base = 0; }
    else if (f < 32768) { src = Wa + 512 * 64; off = f - 16384; M = 256; K = 64;  base = 16384; }
    else if (f < 98304) { src = Wo;            off = f - 32768; M = 256; K = 256; base = 32768; }
    else                { src = Wf;            off = f - 98304; M = 256; K = 256; base = 98304; }
    const int m = off / K, k = off - m * K;
    const float4 v = *(const float4*)&src[off];
    ushort4 o; o.x = f2bf(v.x); o.y = f2bf(v.y); o.z = f2bf(v.z); o.w = f2bf(v.w);
    *(ushort4*)&dst[base + (k >> 5) * (M * 32) + m * 32 + (k & 31)] = o;
}

// x [B,256,NV] fp32 channel-major -> xT [P][256] bf16 position-major
__global__ __launch_bounds__(256) void transpose_kernel(
    const float* __restrict__ x, unsigned short* __restrict__ xT)
{
    __shared__ float T[64][65];
    const int p0 = blockIdx.x * 64;
    const int c0 = blockIdx.y * 64;
    const int b  = p0 / kNV;
    const int q0 = p0 - b * kNV;
    const int t  = threadIdx.x;

    const int cl = t >> 2;
    const int pq = (t & 3) * 16;
    const float* src = &x[(size_t)(b * kC + c0 + cl) * kNV + q0 + pq];
    #pragma unroll
    for (int i = 0; i < 4; ++i) {
        const float4 v = *(const float4*)&src[i * 4];
        T[cl][pq + i * 4 + 0] = v.x;
        T[cl][pq + i * 4 + 1] = v.y;
        T[cl][pq + i * 4 + 2] = v.z;
        T[cl][pq + i * 4 + 3] = v.w;
    }
    __syncthreads();
    const int pr = t >> 2;
    const int cb = (t & 3) * 16;
    #pragma unroll
    for (int i = 0; i < 2; ++i) {
        ushort8 o;
        #pragma unroll
        for (int j = 0; j < 8; ++j) o[j] = f2bf(T[cb + i * 8 + j][pr]);
        *(ushort8*)&xT[(size_t)(p0 + pr) * 256 + c0 + cb + i * 8] = o;
    }
}

template<int MODE>
__device__ __forceinline__ ushort8 xform(ushort8 y8, ushort8 x8, float mp,
                                         const float* __restrict__ actA,
                                         const float* __restrict__ actB, int kk)
{
    if constexpr (MODE == 0) {
        return y8;
    } else {
        const float4 a0 = *(const float4*)&actA[kk];
        const float4 a1 = *(const float4*)&actA[kk + 4];
        const float4 b0 = *(const float4*)&actB[kk];
        const float4 b1 = *(const float4*)&actB[kk + 4];
        const float aa[8] = {a0.x, a0.y, a0.z, a0.w, a1.x, a1.y, a1.z, a1.w};
        const float bb[8] = {b0.x, b0.y, b0.z, b0.w, b1.x, b1.y, b1.z, b1.w};
        float v[8];
        #pragma unroll
        for (int j = 0; j < 8; ++j) {
            float t = mp * fmaxf(fmaf(aa[j], bf2f(y8[j]), bb[j]), 0.f);
            if constexpr (MODE == 2) t += bf2f(x8[j]);
            v[j] = t;
        }
        uint4 u;
        u.x = f2bf2(v[0], v[1]); u.y = f2bf2(v[2], v[3]);
        u.z = f2bf2(v[4], v[5]); u.w = f2bf2(v[6], v[7]);
        return __builtin_bit_cast(ushort8, u);
    }
}

// A-stationary GEMM, wave-count-first layout.
// Block = NW waves x 64 threads; EACH WAVE owns exactly 16 output channels
// (BM = NW*16, FM=1 -> Areg = K/32 x 16B = 32 VGPR at K=256). NW=8 (512-thread)
// blocks double resident waves/CU vs the 4-wave variant (the counters say every
// stage is latency-bound at ~28% occupancy with no resource >35%).
// SIBS sibling blocks split MTOT channels for the same slab range; XCD-grouping
// swizzle co-locates siblings on one XCD (shared B-stream deduped through L2).
// 2-buffer LDS pipeline, ONE counted barrier per slab (lgkmcnt drain only -- no
// vmcnt drain, stores/loads fly across). FP = positions/16 per slab (template).
// BN stats accumulate in registers; flush once via owner-lane atomics.
// MODE 0: B = raw bf16. MODE 1: B = mask*relu(a*y+b). MODE 2: MODE1 + XT residual.
template<int BM, int MTOT, int K, int MODE, int SIBS, int NW, int FP, int MINW>
__global__ __launch_bounds__(NW * 64, MINW) void gemm_kernel(
    const unsigned short* __restrict__ Apk, const float* __restrict__ bias,
    const unsigned short* __restrict__ Yprev, const unsigned short* __restrict__ XT,
    const float* __restrict__ mask,
    const float* __restrict__ pPrev, const float* __restrict__ gPrev,
    const float* __restrict__ btPrev,
    unsigned short* __restrict__ Yout, float* __restrict__ partial, int slabsPerBlock)
{
    constexpr int THREADS = NW * 64;
    constexpr int SLAB = FP * 16;        // positions per slab
    constexpr int LD = K + 8;            // padded row stride (shorts)
    constexpr int NT = K / 32;
    constexpr int KR = K / 8;            // ushort8 chunks per row
    constexpr int CH = SLAB * KR / THREADS;  // chunks per thread per stream
    constexpr int XH = (MODE == 2) ? CH : 1;
    static_assert(BM == NW * 16, "one 16-channel slice per wave");
    __shared__ unsigned short Bs[2][SLAB * LD];
    __shared__ float ActA[256];
    __shared__ float ActB[256];

    const int tid  = threadIdx.x;
    const int w    = tid >> 6, lane = tid & 63, quad = lane >> 4, lt = lane & 15;
    const int mBase = w * 16;

    // ---- block -> (group, sibling). Round-robin dispatch: bid%8 -> XCD bid%8;
    // siblings are 8 apart in bid -> same XCD, adjacent in dispatch order.
    int groupId, sib;
    if constexpr (SIBS > 1) {
        const int x = blockIdx.x & 7;
        const int s = blockIdx.x >> 3;
        const int perX = (int)(gridDim.x >> 3) / SIBS;
        sib = s % SIBS;
        groupId = x * perX + s / SIBS;
    } else {
        groupId = blockIdx.x; sib = 0;
    }
    const int chOff = sib * BM;
    const int spb   = slabsPerBlock;
    const int slab0 = groupId * spb;

    // ---- fold previous stage's BN into per-channel affine (finalize folded in) ----
    if constexpr (MODE != 0) {
        if (tid < K) {
            float s = 0.f, s2 = 0.f;
            #pragma unroll
            for (int k = 0; k < 8; ++k) {
                s  += pPrev[k * 512 + tid];
                s2 += pPrev[k * 512 + 256 + tid];
            }
            const float mu  = s * (1.f / kP);
            const float var = s2 * (1.f / kP) - mu * mu;
            const float A   = rsqrtf(var + kEps) * gPrev[tid];
            ActA[tid] = A;
            ActB[tid] = fmaf(-mu, A, btPrev[tid]);
        }
        __syncthreads();
    }

    // ---- A fragments: full K for this wave's 16-channel slice, in registers ----
    ushort8 Areg[NT];
    #pragma unroll
    for (int t = 0; t < NT; ++t)
        Areg[t] = *(const ushort8*)&Apk[(size_t)(t * MTOT + chOff + mBase + lt) * 32 + quad * 8];

    // ---- bias hoisted to registers (invariant across slabs) ----
    float biR[4];
    {
        const float4 b4 = *(const float4*)&bias[chOff + mBase + quad * 4];
        biR[0] = b4.x; biR[1] = b4.y; biR[2] = b4.z; biR[3] = b4.w;
    }

    // ---- BN stats accumulate in registers across all slabs ----
    float aS[4], aQ[4];
    #pragma unroll
    for (int i = 0; i < 4; ++i) { aS[i] = 0.f; aQ[i] = 0.f; }

    // ---- prologue: stage slab 0 into Bs[0]; current epilogue mask ----
    {
        const int pBase = slab0 * SLAB;
        #pragma unroll
        for (int i = 0; i < CH; ++i) {
            const int c = tid + i * THREADS;
            const int p = c / KR;
            const int kq = (c % KR) * 8;
            const ushort8 y8 = *(const ushort8*)&Yprev[(size_t)(pBase + p) * K + kq];
            ushort8 o;
            if constexpr (MODE == 0) o = y8;
            else {
                ushort8 x8{};
                if constexpr (MODE == 2) x8 = *(const ushort8*)&XT[(size_t)(pBase + p) * K + kq];
                o = xform<MODE>(y8, x8, mask[pBase + p], ActA, ActB, kq);
            }
            *(ushort8*)&Bs[0][p * LD + kq] = o;
        }
    }
    float mCur[FP];
    #pragma unroll
    for (int fp = 0; fp < FP; ++fp) mCur[fp] = mask[slab0 * SLAB + fp * 16 + lt];
    phase_barrier();

    for (int s = 0; s < spb; ++s) {
        const int pBase = (slab0 + s) * SLAB;
        const bool hasNext = (s + 1 < spb);

        // ---- issue next slab's stream + mask loads FIRST ----
        ushort8 py[CH];
        ushort8 px[XH];
        float mxN[CH];
        float mNxt[FP];
        if (hasNext) {
            const int pN = pBase + SLAB;
            #pragma unroll
            for (int i = 0; i < CH; ++i) {
                const int c = tid + i * THREADS;
                const int p = c / KR;
                const int kq = (c % KR) * 8;
                py[i] = *(const ushort8*)&Yprev[(size_t)(pN + p) * K + kq];
                if constexpr (MODE == 2) px[i] = *(const ushort8*)&XT[(size_t)(pN + p) * K + kq];
                if constexpr (MODE != 0) mxN[i] = mask[pN + c / KR];
            }
            #pragma unroll
            for (int fp = 0; fp < FP; ++fp) mNxt[fp] = mask[pN + fp * 16 + lt];
        }

        // ---- MFMA over current slab: LDS B + register A ----
        floatx4 acc[FP];
        #pragma unroll
        for (int fp = 0; fp < FP; ++fp) acc[fp] = (floatx4)0.f;

        const unsigned short* bs = &Bs[s & 1][0];
        #pragma unroll
        for (int t = 0; t < NT; ++t) {
            const bf16x8 aF = __builtin_bit_cast(bf16x8, Areg[t]);
            #pragma unroll
            for (int fp = 0; fp < FP; ++fp) {
                const bf16x8 bF = *(const bf16x8*)&bs[(fp * 16 + lt) * LD + t * 32 + quad * 8];
                acc[fp] = __builtin_amdgcn_mfma_f32_16x16x32_bf16(aF, bF, acc[fp], 0, 0, 0);
            }
        }

        // ---- xform next slab's data into the other buffer ----
        if (hasNext) {
            unsigned short* bn = &Bs[(s + 1) & 1][0];
            #pragma unroll
            for (int i = 0; i < CH; ++i) {
                const int c = tid + i * THREADS;
                const int p = c / KR;
                const int kq = (c % KR) * 8;
                ushort8 o;
                if constexpr (MODE == 0) o = py[i];
                else {
                    ushort8 x8{};
                    if constexpr (MODE == 2) x8 = px[i];
                    o = xform<MODE>(py[i], x8, mxN[i], ActA, ActB, kq);
                }
                *(ushort8*)&bn[p * LD + kq] = o;
            }
        }

        // ---- epilogue: bias + mask, packed bf16 store, stats into registers ----
        #pragma unroll
        for (int fp = 0; fp < FP; ++fp) {
            const int pG = pBase + fp * 16 + lt;
            float vv[4];
            #pragma unroll
            for (int i = 0; i < 4; ++i) {
                const float v = (acc[fp][i] + biR[i]) * mCur[fp];
                vv[i] = v; aS[i] += v; aQ[i] += v * v;
            }
            uint2 o; o.x = f2bf2(vv[0], vv[1]); o.y = f2bf2(vv[2], vv[3]);
            *(uint2*)&Yout[(size_t)pG * MTOT + chOff + mBase + quad * 4] = o;
        }
        if (hasNext) {
            #pragma unroll
            for (int fp = 0; fp < FP; ++fp) mCur[fp] = mNxt[fp];
        }

        phase_barrier();
    }

    // ---- flush stats ONCE: butterfly over the 16-lane group + owner-lane atomics ----
    #pragma unroll
    for (int i = 0; i < 4; ++i) {
        #pragma unroll
        for (int off = 1; off < 16; off <<= 1) {
            aS[i] += __shfl_xor(aS[i], off);
            aQ[i] += __shfl_xor(aQ[i], off);
        }
    }
    if (lt == 0) {
        float* pb = partial + (size_t)(blockIdx.x & 7) * 512;
        #pragma unroll
        for (int i = 0; i < 4; ++i) {
            const int ch = chOff + mBase + quad * 4 + i;  // unique owner
            atomicAdd(&pb[ch], aS[i]);
            atomicAdd(&pb[256 + ch], aQ[i]);
        }
    }
}

// out[c][q] = x1 + act4(y4), with x1 = x + act3(y3) recomputed on the fly.
// Both act3 and act4 affines computed in-prologue from the part buckets.
__global__ __launch_bounds__(256) void final_kernel(
    const unsigned short* __restrict__ xT, const unsigned short* __restrict__ y3,
    const unsigned short* __restrict__ y4,
    const float* __restrict__ p3, const float* __restrict__ g3, const float* __restrict__ bt3,
    const float* __restrict__ p4, const float* __restrict__ g4, const float* __restrict__ bt4,
    const float* __restrict__ mask, float* __restrict__ out)
{
    constexpr int TL = 264;
    __shared__ unsigned short TX[32 * TL];   // x1 (bf16)
    __shared__ unsigned short T4[32 * TL];   // y4 raw
    __shared__ float PA3[256], PB3[256], PA4[256], PB4[256];
    const int p0 = blockIdx.x * 32;
    const int b  = p0 / kNV;
    const int q0 = p0 - b * kNV;

    {
        const int m = threadIdx.x;
        float s3 = 0.f, q3 = 0.f, s4 = 0.f, q4 = 0.f;
        #pragma unroll
        for (int k = 0; k < 8; ++k) {
            s3 += p3[k * 512 + m]; q3 += p3[k * 512 + 256 + m];
            s4 += p4[k * 512 + m]; q4 += p4[k * 512 + 256 + m];
        }
        const float mu3 = s3 * (1.f / kP);
        const float A3  = rsqrtf(q3 * (1.f / kP) - mu3 * mu3 + kEps) * g3[m];
        PA3[m] = A3; PB3[m] = fmaf(-mu3, A3, bt3[m]);
        const float mu4 = s4 * (1.f / kP);
        const float A4  = rsqrtf(q4 * (1.f / kP) - mu4 * mu4 + kEps) * g4[m];
        PA4[m] = A4; PB4[m] = fmaf(-mu4, A4, bt4[m]);
    }
    __syncthreads();

    #pragma unroll
    for (int i = 0; i < 4; ++i) {
        const int idx = threadIdx.x + i * 256;
        const int p = idx >> 5, c0 = (idx & 31) * 8;
        const ushort8 x8  = *(const ushort8*)&xT[(size_t)(p0 + p) * 256 + c0];
        const ushort8 y38 = *(const ushort8*)&y3[(size_t)(p0 + p) * 256 + c0];
        const ushort8 y48 = *(const ushort8*)&y4[(size_t)(p0 + p) * 256 + c0];
        const float mp = mask[p0 + p];
        ushort8 o;
        #pragma unroll
        for (int j = 0; j < 8; ++j) {
            const int c = c0 + j;
            const float x1 = bf2f(x8[j]) + mp * fmaxf(fmaf(PA3[c], bf2f(y38[j]), PB3[c]), 0.f);
            o[j] = f2bf(x1);
        }
        *(ushort8*)&TX[p * TL + c0] = o;
        *(ushort8*)&T4[p * TL + c0] = y48;
    }
    __syncthreads();

    const int qv = (threadIdx.x & 15) * 2;
    const int cb = threadIdx.x >> 4;
    const float m0v = mask[p0 + qv], m1v = mask[p0 + qv + 1];
    #pragma unroll
    for (int j = 0; j < 16; ++j) {
        const int c = cb + j * 16;
        const float a4 = PA4[c], b4 = PB4[c];
        const size_t ro = (size_t)(b * kC + c) * kNV + q0 + qv;
        float2 o;
        o.x = bf2f(TX[qv * TL + c])       + m0v * fmaxf(fmaf(a4, bf2f(T4[qv * TL + c]), b4), 0.f);
        o.y = bf2f(TX[(qv + 1) * TL + c]) + m1v * fmaxf(fmaf(a4, bf2f(T4[(qv + 1) * TL + c]), b4), 0.f);
        *(float2*)&out[ro] = o;
    }
}

extern "C" void kernel_launch(void* const* d_in, const int* in_sizes, int n_in,
                              void* d_out, int out_size, void* d_ws, size_t ws_size,
                              hipStream_t stream)
{
    const float* x    = (const float*)d_in[0];
    const float* mask = (const float*)d_in[1];
    const float* We   = (const float*)d_in[2];
    const float* be   = (const float*)d_in[3];
    const float* ge   = (const float*)d_in[4];
    const float* bne  = (const float*)d_in[5];
    const float* Wa   = (const float*)d_in[6];
    const float* ba   = (const float*)d_in[7];
    const float* ga   = (const float*)d_in[8];
    const float* bna  = (const float*)d_in[9];
    const float* Wo   = (const float*)d_in[10];
    const float* bo   = (const float*)d_in[11];
    const float* go   = (const float*)d_in[12];
    const float* bno  = (const float*)d_in[13];
    const float* Wf   = (const float*)d_in[14];
    const float* bf   = (const float*)d_in[15];
    const float* gf   = (const float*)d_in[16];
    const float* bnf  = (const float*)d_in[17];
    float* out = (float*)d_out;
    float* ws  = (float*)d_ws;

    float* part = ws + OFF_PART;
    unsigned short* Wb = (unsigned short*)(ws + OFF_WB);
    unsigned short* xT = (unsigned short*)(ws + OFF_XT);
    unsigned short* y1 = (unsigned short*)(ws + OFF_Y1);
    unsigned short* y2 = (unsigned short*)(ws + OFF_Y2);   // later reused as y4
    unsigned short* y3 = (unsigned short*)(ws + OFF_Y3);

    hipMemsetAsync(part, 0, 16384 * sizeof(float), stream);
    convw_kernel<<<160, 256, 0, stream>>>(We, Wa, Wo, Wf, Wb);
    transpose_kernel<<<dim3(kP / 64, 4), 256, 0, stream>>>(x, xT);

    // stage 1: y1 = mask*(We @ x + be)  [P][64]      4-wave blocks (as r6)
    gemm_kernel<64, 64, 256, 0, 1, 4, 2, 3><<<768, 256, 0, stream>>>(
        Wb, be, xT, nullptr, mask, nullptr, nullptr, nullptr, y1, part, 4);

    // stage 2: y2 = mask*(Wa_v @ act1(y1) + ba_v)    8-wave, 64-pos slabs, 2 sibs
    gemm_kernel<128, 256, 64, 1, 2, 8, 4, 4><<<768, 512, 0, stream>>>(
        Wb + 16384, ba + 512, y1, nullptr, mask, part, ge, bne, y2, part + 4096, 4);

    // stage 3: y3 = mask*(Wo @ act2(y2) + bo)        8-wave, 2 sibs
    gemm_kernel<128, 256, 256, 1, 2, 8, 2, 4><<<768, 512, 0, stream>>>(
        Wb + 32768, bo, y2, nullptr, mask, part + 4096, ga + 512, bna + 512, y3, part + 8192, 8);

    // stage 4: y4 = mask*(Wf @ (x + act3(y3)) + bf)  XT read-only, 8-wave, 2 sibs
    gemm_kernel<128, 256, 256, 2, 2, 8, 2, 4><<<768, 512, 0, stream>>>(
        Wb + 98304, bf, y3, xT, mask, part + 8192, go, bno, y2, part + 12288, 8);

    // final: out = (x + act3(y3)) + act4(y4)
    final_kernel<<<kP / 32, 256, 0, stream>>>(
        xT, y3, y2, part + 8192, go, bno, part + 12288, gf, bnf, mask, out);
}